// Round 5
// baseline (106.058 us; speedup 1.0000x reference)
//
#include <hip/hip_runtime.h>
#include <stdint.h>

#define BB    4
#define CC    320
#define HH    135
#define WW    240
#define HW    (HH*WW)      // 32400
#define PNUM  12960
#define NBUCK 16384
#define MAXPER 32
#define P4    (HW/4)       // 8100
#define NCH   4
#define NCG   (CC/NCH)     // 80
#define NTILE (NCG*P4)     // 648000

typedef float f4 __attribute__((ext_vector_type(4)));
typedef unsigned u4 __attribute__((ext_vector_type(4)));

__device__ inline unsigned short f2bf(float x) {   // round-to-nearest-even
    unsigned u = __float_as_uint(x);
    return (unsigned short)((u + 0x7fffu + ((u >> 16) & 1u)) >> 16);
}

// ---- Pass 0: zero the histogram ----
__global__ __launch_bounds__(256) void k_zero(unsigned* __restrict__ hist) {
    int i = blockIdx.x * 256 + threadIdx.x;
    if (i < NBUCK) hist[i] = 0u;
}

// ---- Pass 1: bucket each pixel by value ----
__global__ __launch_bounds__(256) void k_bucket(const float* __restrict__ unc,
                                                unsigned* __restrict__ hist,
                                                unsigned* __restrict__ members) {
    int i = blockIdx.x * 256 + threadIdx.x;
    if (i >= HW) return;
    float v = unc[i];
    int b = (int)(v * (float)NBUCK);
    b = b < 0 ? 0 : (b > NBUCK - 1 ? NBUCK - 1 : b);
    unsigned pos = atomicAdd(&hist[b], 1u);
    if (pos < MAXPER) members[(unsigned)b * MAXPER + pos] = (unsigned)i;
}

// ---- Pass 2: suffix-count ----
__global__ __launch_bounds__(1024) void k_scan(const unsigned* __restrict__ hist,
                                               unsigned* __restrict__ base) {
    __shared__ unsigned sh[1024];
    const int CH = NBUCK / 1024;
    int t = threadIdx.x;
    unsigned loc[CH];
    unsigned s = 0;
    #pragma unroll
    for (int k = 0; k < CH; ++k) { loc[k] = hist[t * CH + k]; s += loc[k]; }
    sh[t] = s;
    __syncthreads();
    for (int off = 1; off < 1024; off <<= 1) {
        unsigned v = (t + off < 1024) ? sh[t + off] : 0u;
        __syncthreads();
        sh[t] += v;
        __syncthreads();
    }
    unsigned run = sh[t] - s;
    #pragma unroll
    for (int k = CH - 1; k >= 0; --k) { base[t * CH + k] = run; run += loc[k]; }
}

// ---- Pass 3: exact descending rank, (value desc, index asc) tie-break ----
__global__ __launch_bounds__(256) void k_rank(const float* __restrict__ unc,
                                              const unsigned* __restrict__ hist,
                                              const unsigned* __restrict__ base,
                                              const unsigned* __restrict__ members,
                                              unsigned* __restrict__ rank) {
    int i = blockIdx.x * 256 + threadIdx.x;
    if (i >= HW) return;
    float vi = unc[i];
    int b = (int)(vi * (float)NBUCK);
    b = b < 0 ? 0 : (b > NBUCK - 1 ? NBUCK - 1 : b);
    unsigned cnt = hist[b];
    if (cnt > MAXPER) cnt = MAXPER;
    unsigned r = base[b];
    for (unsigned k = 0; k < cnt; ++k) {
        unsigned j = members[(unsigned)b * MAXPER + k];
        if (j == (unsigned)i) continue;
        float vj = unc[j];
        r += (vj > vi) || (vj == vi && j < (unsigned)i);
    }
    rank[i] = r;
}

// ---- Pass 4a: materialize dense bf16 delta, pixel-ordered ----
// dbuf[cg*HW + p] = uint2 {bf16(ch c0),bf16(c0+1) | bf16(c0+2),bf16(c0+3)}
__global__ __launch_bounds__(256) void k_gather(const float* __restrict__ prompts,
                                                const unsigned* __restrict__ rank,
                                                unsigned* __restrict__ dbuf) {
    int t = blockIdx.x * 256 + threadIdx.x;      // t = cg*HW + p
    if (t >= NCG * HW) return;
    int cg = t / HW;
    int p  = t - cg * HW;
    unsigned r = rank[p];
    f4 gv = (f4)(0.0f);
    if (r < PNUM) gv = *(const f4*)(prompts + (size_t)r * CC + cg * 4);
    uint2 w;
    w.x = (unsigned)f2bf(gv[0]) | ((unsigned)f2bf(gv[1]) << 16);
    w.y = (unsigned)f2bf(gv[2]) | ((unsigned)f2bf(gv[3]) << 16);
    *(uint2*)(dbuf + 2 * (size_t)t) = w;
}

// ---- Pass 4b: PURE STREAM: out = x + unpack(dbuf). No scattered accesses.
// Plain loads/stores, exactly the m13-copy configuration plus one linear read.
__global__ __launch_bounds__(256) void k_apply2(const float* __restrict__ x,
                                                const unsigned* __restrict__ dbuf,
                                                float* __restrict__ out) {
    int t = blockIdx.x * 256 + threadIdx.x;
    if (t >= NTILE) return;
    int cg = t / P4;
    int p4 = t - cg * P4;
    int c0 = cg * NCH;
    int p  = p4 * 4;

    const unsigned* dp = dbuf + 2 * ((size_t)cg * HW + p);   // 32B, 32B-aligned
    u4 A  = *(const u4*)dp;
    u4 Bv = *(const u4*)(dp + 4);

    float g[4][4];
    #pragma unroll
    for (int k = 0; k < 4; ++k) {
        unsigned w0 = (k < 2) ? A[2 * k]     : Bv[2 * k - 4];
        unsigned w1 = (k < 2) ? A[2 * k + 1] : Bv[2 * k - 3];
        g[k][0] = __uint_as_float(w0 << 16);
        g[k][1] = __uint_as_float(w0 & 0xffff0000u);
        g[k][2] = __uint_as_float(w1 << 16);
        g[k][3] = __uint_as_float(w1 & 0xffff0000u);
    }

    #pragma unroll
    for (int b = 0; b < BB; ++b) {
        #pragma unroll
        for (int j = 0; j < NCH; ++j) {
            int off = (b * CC + c0 + j) * HW + p;
            f4 xv = *(const f4*)(x + off);
            xv[0] += g[0][j]; xv[1] += g[1][j]; xv[2] += g[2][j]; xv[3] += g[3][j];
            *(f4*)(out + off) = xv;
        }
    }
}

// ---- Fallback single-pass (R4 path) if ws too small for dbuf ----
#define OFFS(it) ((((it) >> 2) * CC + c0 + ((it) & 3)) * HW + p)
__global__ __launch_bounds__(256) void k_apply1(const float* __restrict__ x,
                                                const float* __restrict__ prompts,
                                                const unsigned* __restrict__ rank,
                                                float* __restrict__ out) {
    int t = blockIdx.x * 256 + threadIdx.x;
    if (t >= NTILE) return;
    int cg = t / P4;
    int p4 = t - cg * P4;
    int c0 = cg * NCH;
    int p  = p4 * 4;
    u4 r4 = *(const u4*)(rank + p);
    float g[4][NCH];
    #pragma unroll
    for (int k = 0; k < 4; ++k) {
        unsigned r = r4[k];
        f4 gv = (f4)(0.0f);
        if (r < PNUM) gv = *(const f4*)(prompts + (size_t)r * CC + c0);
        #pragma unroll
        for (int j = 0; j < NCH; ++j) g[k][j] = gv[j];
    }
    #pragma unroll
    for (int b = 0; b < BB; ++b) {
        #pragma unroll
        for (int j = 0; j < NCH; ++j) {
            int off = (b * CC + c0 + j) * HW + p;
            f4 xv = __builtin_nontemporal_load((const f4*)(x + off));
            xv[0] += g[0][j]; xv[1] += g[1][j]; xv[2] += g[2][j]; xv[3] += g[3][j];
            __builtin_nontemporal_store(xv, (f4*)(out + off));
        }
    }
}

extern "C" void kernel_launch(void* const* d_in, const int* in_sizes, int n_in,
                              void* d_out, int out_size, void* d_ws, size_t ws_size,
                              hipStream_t stream) {
    const float* x       = (const float*)d_in[0];
    const float* unc     = (const float*)d_in[1];
    const float* prompts = (const float*)d_in[2];
    float* out = (float*)d_out;

    char* ws = (char*)d_ws;
    unsigned* hist    = (unsigned*)(ws);
    unsigned* base    = (unsigned*)(ws + 65536);
    unsigned* members = (unsigned*)(ws + 131072);
    unsigned* rank    = (unsigned*)(ws + 131072 + 2097152);
    unsigned* dbuf    = (unsigned*)(ws + 131072 + 2097152 + 129792);
    const size_t need = 131072 + 2097152 + 129792 + (size_t)NCG * HW * 8;  // ~23.1 MB

    k_zero<<<NBUCK / 256, 256, 0, stream>>>(hist);
    k_bucket<<<(HW + 255) / 256, 256, 0, stream>>>(unc, hist, members);
    k_scan<<<1, 1024, 0, stream>>>(hist, base);
    k_rank<<<(HW + 255) / 256, 256, 0, stream>>>(unc, hist, base, members, rank);

    if (ws_size >= need) {
        k_gather<<<(NCG * HW) / 256, 256, 0, stream>>>(prompts, rank, dbuf);
        k_apply2<<<(NTILE + 255) / 256, 256, 0, stream>>>(x, dbuf, out);
    } else {
        k_apply1<<<(NTILE + 255) / 256, 256, 0, stream>>>(x, prompts, rank, out);
    }
}

// Round 6
// 104.716 us; speedup vs baseline: 1.0128x; 1.0128x over previous
//
#include <hip/hip_runtime.h>
#include <stdint.h>

#define BB    4
#define CC    320
#define HH    135
#define WW    240
#define HW    (HH*WW)      // 32400
#define PNUM  12960
#define NBUCK 16384
#define MAXPER 32
#define P4    (HW/4)       // 8100
#define NCH   4
#define NCG   (CC/NCH)     // 80
#define NTILE (NCG*P4)     // 648000 (fallback path)
#define OCT   (HW/8)       // 4050

typedef float f4 __attribute__((ext_vector_type(4)));
typedef unsigned u4 __attribute__((ext_vector_type(4)));
typedef unsigned short us8 __attribute__((ext_vector_type(8)));

__device__ inline unsigned short f2bf(float x) {   // round-to-nearest-even
    unsigned u = __float_as_uint(x);
    return (unsigned short)((u + 0x7fffu + ((u >> 16) & 1u)) >> 16);
}

// ---- Pass 0: zero the histogram ----
__global__ __launch_bounds__(256) void k_zero(unsigned* __restrict__ hist) {
    int i = blockIdx.x * 256 + threadIdx.x;
    if (i < NBUCK) hist[i] = 0u;
}

// ---- Pass 1: bucket each pixel by value ----
__global__ __launch_bounds__(256) void k_bucket(const float* __restrict__ unc,
                                                unsigned* __restrict__ hist,
                                                unsigned* __restrict__ members) {
    int i = blockIdx.x * 256 + threadIdx.x;
    if (i >= HW) return;
    float v = unc[i];
    int b = (int)(v * (float)NBUCK);
    b = b < 0 ? 0 : (b > NBUCK - 1 ? NBUCK - 1 : b);
    unsigned pos = atomicAdd(&hist[b], 1u);
    if (pos < MAXPER) members[(unsigned)b * MAXPER + pos] = (unsigned)i;
}

// ---- Pass 2: suffix-count ----
__global__ __launch_bounds__(1024) void k_scan(const unsigned* __restrict__ hist,
                                               unsigned* __restrict__ base) {
    __shared__ unsigned sh[1024];
    const int CH = NBUCK / 1024;
    int t = threadIdx.x;
    unsigned loc[CH];
    unsigned s = 0;
    #pragma unroll
    for (int k = 0; k < CH; ++k) { loc[k] = hist[t * CH + k]; s += loc[k]; }
    sh[t] = s;
    __syncthreads();
    for (int off = 1; off < 1024; off <<= 1) {
        unsigned v = (t + off < 1024) ? sh[t + off] : 0u;
        __syncthreads();
        sh[t] += v;
        __syncthreads();
    }
    unsigned run = sh[t] - s;
    #pragma unroll
    for (int k = CH - 1; k >= 0; --k) { base[t * CH + k] = run; run += loc[k]; }
}

// ---- Pass 3: exact descending rank, (value desc, index asc) tie-break ----
__global__ __launch_bounds__(256) void k_rank(const float* __restrict__ unc,
                                              const unsigned* __restrict__ hist,
                                              const unsigned* __restrict__ base,
                                              const unsigned* __restrict__ members,
                                              unsigned* __restrict__ rank) {
    int i = blockIdx.x * 256 + threadIdx.x;
    if (i >= HW) return;
    float vi = unc[i];
    int b = (int)(vi * (float)NBUCK);
    b = b < 0 ? 0 : (b > NBUCK - 1 ? NBUCK - 1 : b);
    unsigned cnt = hist[b];
    if (cnt > MAXPER) cnt = MAXPER;
    unsigned r = base[b];
    for (unsigned k = 0; k < cnt; ++k) {
        unsigned j = members[(unsigned)b * MAXPER + k];
        if (j == (unsigned)i) continue;
        float vj = unc[j];
        r += (vj > vi) || (vj == vi && j < (unsigned)i);
    }
    rank[i] = r;
}

// ---- Pass 4a: materialize bf16 delta as channel planes dbufp[c][p] ----
// Thread = (cg, octet of 8 pixels): 8 gathers of 16B, writes 4 planes x 16B
// (lane-adjacent threads -> 1KB contiguous per plane per wave).
__global__ __launch_bounds__(256) void k_gather(const float* __restrict__ prompts,
                                                const unsigned* __restrict__ rank,
                                                unsigned short* __restrict__ dbufp) {
    int t = blockIdx.x * 256 + threadIdx.x;
    if (t >= NCG * OCT) return;
    int cg = t / OCT;
    int o8 = t - cg * OCT;
    int p0 = o8 * 8;

    u4 ra = *(const u4*)(rank + p0);
    u4 rb = *(const u4*)(rank + p0 + 4);

    unsigned short w[NCH][8];
    #pragma unroll
    for (int k = 0; k < 8; ++k) {
        unsigned r = (k < 4) ? ra[k] : rb[k - 4];
        f4 gv = (f4)(0.0f);
        if (r < PNUM) gv = *(const f4*)(prompts + (size_t)r * CC + cg * 4);
        #pragma unroll
        for (int j = 0; j < NCH; ++j) w[j][k] = f2bf(gv[j]);
    }
    #pragma unroll
    for (int j = 0; j < NCH; ++j) {
        us8 v;
        #pragma unroll
        for (int k = 0; k < 8; ++k) v[k] = w[j][k];
        *(us8*)(dbufp + (size_t)(cg * NCH + j) * HW + p0) = v;
    }
}

// ---- Pass 4b: FLAT copy-shaped stream: out = x + bf16plane. ----
// Grid: y = (b*CC + c) slice [1280], x = 32 blocks of 256 float4s.
// One 16B load + one coalesced 8B load + one 16B store per thread. No per-lane
// division, no strided iteration — structurally identical to a flat d2d copy.
__global__ __launch_bounds__(256) void k_apply3(const float* __restrict__ x,
                                                const unsigned short* __restrict__ dbufp,
                                                float* __restrict__ out) {
    int p4 = blockIdx.x * 256 + threadIdx.x;
    if (p4 >= P4) return;
    int slice = blockIdx.y;            // b*CC + c  (uniform)
    int c = slice % CC;                // scalar div-by-const
    size_t off = (size_t)slice * HW + 4 * (size_t)p4;

    uint2 d = *(const uint2*)(dbufp + (size_t)c * HW + 4 * p4);
    f4 xv = *(const f4*)(x + off);
    xv[0] += __uint_as_float(d.x << 16);
    xv[1] += __uint_as_float(d.x & 0xffff0000u);
    xv[2] += __uint_as_float(d.y << 16);
    xv[3] += __uint_as_float(d.y & 0xffff0000u);
    *(f4*)(out + off) = xv;
}

// ---- Fallback single-pass (R4 path) if ws too small ----
__global__ __launch_bounds__(256) void k_apply1(const float* __restrict__ x,
                                                const float* __restrict__ prompts,
                                                const unsigned* __restrict__ rank,
                                                float* __restrict__ out) {
    int t = blockIdx.x * 256 + threadIdx.x;
    if (t >= NTILE) return;
    int cg = t / P4;
    int p4 = t - cg * P4;
    int c0 = cg * NCH;
    int p  = p4 * 4;
    u4 r4 = *(const u4*)(rank + p);
    float g[4][NCH];
    #pragma unroll
    for (int k = 0; k < 4; ++k) {
        unsigned r = r4[k];
        f4 gv = (f4)(0.0f);
        if (r < PNUM) gv = *(const f4*)(prompts + (size_t)r * CC + c0);
        #pragma unroll
        for (int j = 0; j < NCH; ++j) g[k][j] = gv[j];
    }
    #pragma unroll
    for (int b = 0; b < BB; ++b) {
        #pragma unroll
        for (int j = 0; j < NCH; ++j) {
            int off = (b * CC + c0 + j) * HW + p;
            f4 xv = __builtin_nontemporal_load((const f4*)(x + off));
            xv[0] += g[0][j]; xv[1] += g[1][j]; xv[2] += g[2][j]; xv[3] += g[3][j];
            __builtin_nontemporal_store(xv, (f4*)(out + off));
        }
    }
}

extern "C" void kernel_launch(void* const* d_in, const int* in_sizes, int n_in,
                              void* d_out, int out_size, void* d_ws, size_t ws_size,
                              hipStream_t stream) {
    const float* x       = (const float*)d_in[0];
    const float* unc     = (const float*)d_in[1];
    const float* prompts = (const float*)d_in[2];
    float* out = (float*)d_out;

    char* ws = (char*)d_ws;
    unsigned* hist         = (unsigned*)(ws);
    unsigned* base         = (unsigned*)(ws + 65536);
    unsigned* members      = (unsigned*)(ws + 131072);
    unsigned* rank         = (unsigned*)(ws + 131072 + 2097152);
    unsigned short* dbufp  = (unsigned short*)(ws + 131072 + 2097152 + 131072);
    const size_t need = 131072 + 2097152 + 131072 + (size_t)CC * HW * 2;  // ~23.1 MB

    k_zero<<<NBUCK / 256, 256, 0, stream>>>(hist);
    k_bucket<<<(HW + 255) / 256, 256, 0, stream>>>(unc, hist, members);
    k_scan<<<1, 1024, 0, stream>>>(hist, base);
    k_rank<<<(HW + 255) / 256, 256, 0, stream>>>(unc, hist, base, members, rank);

    if (ws_size >= need) {
        k_gather<<<(NCG * OCT + 255) / 256, 256, 0, stream>>>(prompts, rank, dbufp);
        dim3 g((P4 + 255) / 256, BB * CC);
        k_apply3<<<g, 256, 0, stream>>>(x, dbufp, out);
    } else {
        k_apply1<<<(NTILE + 255) / 256, 256, 0, stream>>>(x, prompts, rank, out);
    }
}

// Round 7
// 90.006 us; speedup vs baseline: 1.1783x; 1.1634x over previous
//
#include <hip/hip_runtime.h>
#include <stdint.h>

#define BB    4
#define CC    320
#define HH    135
#define WW    240
#define HW    (HH*WW)      // 32400
#define PNUM  12960
#define NBUCK 16384
#define MAXPER 32
#define P4    (HW/4)       // 8100
#define NCH   4
#define NCG   (CC/NCH)     // 80
#define NTILE (NCG*P4)     // 648000

typedef float f4 __attribute__((ext_vector_type(4)));
typedef unsigned u4 __attribute__((ext_vector_type(4)));

// ---- Pass 0: zero the histogram ----
__global__ __launch_bounds__(256) void k_zero(unsigned* __restrict__ hist) {
    int i = blockIdx.x * 256 + threadIdx.x;
    if (i < NBUCK) hist[i] = 0u;
}

// ---- Pass 1: bucket each pixel by value ----
__global__ __launch_bounds__(256) void k_bucket(const float* __restrict__ unc,
                                                unsigned* __restrict__ hist,
                                                unsigned* __restrict__ members) {
    int i = blockIdx.x * 256 + threadIdx.x;
    if (i >= HW) return;
    float v = unc[i];
    int b = (int)(v * (float)NBUCK);
    b = b < 0 ? 0 : (b > NBUCK - 1 ? NBUCK - 1 : b);
    unsigned pos = atomicAdd(&hist[b], 1u);
    if (pos < MAXPER) members[(unsigned)b * MAXPER + pos] = (unsigned)i;
}

// ---- Pass 2: suffix-count ----
__global__ __launch_bounds__(1024) void k_scan(const unsigned* __restrict__ hist,
                                               unsigned* __restrict__ base) {
    __shared__ unsigned sh[1024];
    const int CH = NBUCK / 1024;
    int t = threadIdx.x;
    unsigned loc[CH];
    unsigned s = 0;
    #pragma unroll
    for (int k = 0; k < CH; ++k) { loc[k] = hist[t * CH + k]; s += loc[k]; }
    sh[t] = s;
    __syncthreads();
    for (int off = 1; off < 1024; off <<= 1) {
        unsigned v = (t + off < 1024) ? sh[t + off] : 0u;
        __syncthreads();
        sh[t] += v;
        __syncthreads();
    }
    unsigned run = sh[t] - s;
    #pragma unroll
    for (int k = CH - 1; k >= 0; --k) { base[t * CH + k] = run; run += loc[k]; }
}

// ---- Pass 3: exact descending rank, (value desc, index asc) tie-break ----
__global__ __launch_bounds__(256) void k_rank(const float* __restrict__ unc,
                                              const unsigned* __restrict__ hist,
                                              const unsigned* __restrict__ base,
                                              const unsigned* __restrict__ members,
                                              unsigned* __restrict__ rank) {
    int i = blockIdx.x * 256 + threadIdx.x;
    if (i >= HW) return;
    float vi = unc[i];
    int b = (int)(vi * (float)NBUCK);
    b = b < 0 ? 0 : (b > NBUCK - 1 ? NBUCK - 1 : b);
    unsigned cnt = hist[b];
    if (cnt > MAXPER) cnt = MAXPER;
    unsigned r = base[b];
    for (unsigned k = 0; k < cnt; ++k) {
        unsigned j = members[(unsigned)b * MAXPER + k];
        if (j == (unsigned)i) continue;
        float vj = unc[j];
        r += (vj > vi) || (vj == vi && j < (unsigned)i);
    }
    rank[i] = r;
}

// ---- Pass 4: fused out = x + scatter(prompts), BURST-structured ----
// R4 tiling (4ch x 4pix x 4batch per thread, 648k threads) but the 16
// load/add/store iterations become 2x { 8 NT loads | sched_barrier | 8 add+NT
// stores }: 8KB-per-wave read bursts alternating with 8KB write bursts,
// instead of 1KB-interleaved R/W. Tests the DRAM bus-turnaround theory.
__global__ __launch_bounds__(256) void k_apply(const float* __restrict__ x,
                                               const float* __restrict__ prompts,
                                               const unsigned* __restrict__ rank,
                                               float* __restrict__ out) {
    int t = blockIdx.x * 256 + threadIdx.x;
    if (t >= NTILE) return;
    int cg = t / P4;
    int p4 = t - cg * P4;
    int c0 = cg * NCH;
    int p  = p4 * 4;

    u4 r4 = *(const u4*)(rank + p);

    float g[4][NCH];
    #pragma unroll
    for (int k = 0; k < 4; ++k) {
        unsigned r = r4[k];
        f4 gv = (f4)(0.0f);
        if (r < PNUM) gv = *(const f4*)(prompts + (size_t)r * CC + c0);
        #pragma unroll
        for (int j = 0; j < NCH; ++j) g[k][j] = gv[j];
    }

    #pragma unroll
    for (int half = 0; half < 2; ++half) {
        f4 xv[8];
        // ---- read burst: 8 independent 16B NT loads in flight ----
        #pragma unroll
        for (int q = 0; q < 8; ++q) {
            int it = half * 8 + q;
            int b = it >> 2, j = it & 3;
            xv[q] = __builtin_nontemporal_load(
                        (const f4*)(x + (b * CC + c0 + j) * HW + p));
        }
        __builtin_amdgcn_sched_barrier(0);   // keep stores from interleaving up
        // ---- write burst: 8 add + NT stores ----
        #pragma unroll
        for (int q = 0; q < 8; ++q) {
            int it = half * 8 + q;
            int b = it >> 2, j = it & 3;
            f4 v = xv[q];
            v[0] += g[0][j]; v[1] += g[1][j]; v[2] += g[2][j]; v[3] += g[3][j];
            __builtin_nontemporal_store(v, (f4*)(out + (b * CC + c0 + j) * HW + p));
        }
    }
}

extern "C" void kernel_launch(void* const* d_in, const int* in_sizes, int n_in,
                              void* d_out, int out_size, void* d_ws, size_t ws_size,
                              hipStream_t stream) {
    const float* x       = (const float*)d_in[0];
    const float* unc     = (const float*)d_in[1];
    const float* prompts = (const float*)d_in[2];
    float* out = (float*)d_out;

    char* ws = (char*)d_ws;
    unsigned* hist    = (unsigned*)(ws);
    unsigned* base    = (unsigned*)(ws + 65536);
    unsigned* members = (unsigned*)(ws + 131072);
    unsigned* rank    = (unsigned*)(ws + 131072 + 2097152);

    k_zero<<<NBUCK / 256, 256, 0, stream>>>(hist);
    k_bucket<<<(HW + 255) / 256, 256, 0, stream>>>(unc, hist, members);
    k_scan<<<1, 1024, 0, stream>>>(hist, base);
    k_rank<<<(HW + 255) / 256, 256, 0, stream>>>(unc, hist, base, members, rank);
    k_apply<<<(NTILE + 255) / 256, 256, 0, stream>>>(x, prompts, rank, out);
}